// Round 15
// baseline (104.571 us; speedup 1.0000x reference)
//
#include <hip/hip_runtime.h>
#include <math.h>

#define N_NODES_C 8000
#define N_EDGES_C 64000

static constexpr float PW0_C     = 0.14433756729740646f;   // sqrt(1/48)
static constexpr float C1_C      = 0.14433756729740643f;   // PW1 * INV_SQRT3
static constexpr float PW0IS3_C  = 0.08333333333333333f;   // PW0 * INV_SQRT3
static constexpr float RS32_C    = 0.17677669529663687f;   // 1/sqrt(32)

typedef __attribute__((ext_vector_type(8))) short short8;
typedef __attribute__((ext_vector_type(4))) float f32x4;

__device__ __forceinline__ float silu_f(float x) { return x / (1.0f + expf(-x)); }

__device__ __forceinline__ unsigned short f2bf(float x) {
    union { float f; unsigned u; } a; a.f = x;
    unsigned r = a.u + 0x7fffu + ((a.u >> 16) & 1u);   // RNE
    return (unsigned short)(r >> 16);
}
__device__ __forceinline__ float bf2f(unsigned short x) {
    union { unsigned u; float f; } a; a.u = ((unsigned)x) << 16; return a.f;
}

// Transpose rW2 (64 x 2304 f32) -> rW2T (2304 x 64 bf16). Coalesced reads.
__global__ __launch_bounds__(256) void prep_kernel(
    const float* __restrict__ rW2, unsigned short* __restrict__ rW2T)
{
    const int idx = blockIdx.x * 256 + threadIdx.x;
    const int k = idx / 2304, col = idx % 2304;
    rW2T[(size_t)col * 64 + k] = f2bf(rW2[idx]);
}

// MFMA edge kernel: 128 edges/block, 4 waves x 2 n-tiles (32 edges/wave).
// R15: BARRIER-FREE main loop. Weights read per-wave from L2 directly into
// registers, prefetched one chunk ahead (afA/afB named sets, unroll-by-2).
// No gload_lds, no weight ds_reads, no in-loop barriers — waves are fully
// independent streams. Geometry/EPI/scatter identical to R11.
__global__ __launch_bounds__(256, 2) void edge_kernel_mfma(
    const float* __restrict__ nf,
    const int*   __restrict__ ei,
    const float* __restrict__ sh,
    const float* __restrict__ emb,
    const float* __restrict__ rW1,
    const float* __restrict__ rb1,
    const unsigned short* __restrict__ rW2T,
    const float* __restrict__ rb2,
    float* __restrict__ agg)
{
    __shared__ float rb2_s[2304];           // 9216B
    __shared__ float rW1_s[512];            // 2048B
    __shared__ unsigned short xs_s[128][34];// 8704B bf16
    __shared__ unsigned short xv_s[128][50];// 12800B bf16
    __shared__ float dv_s[128][17];         // 8704B f32
    __shared__ float sh0_s[128];            // 512B
    __shared__ float shv_s[128][3];         // 1536B
    __shared__ int   dst_s[128];            // 512B
    __shared__ float msg[64][84];           // 21504B   -> total 65536B (2 blocks/CU)

    const int t    = threadIdx.x;
    const int e0   = blockIdx.x * 128;
    const int lane = t & 63, wv = t >> 6;
    const int l15  = lane & 15, lk = lane >> 4;

    // --- prologue part 1 ---
    if (t < 128) {
        const int eid = e0 + t;
        dst_s[t] = ei[N_EDGES_C + eid];
        const float4 s4 = *reinterpret_cast<const float4*>(sh + (size_t)eid * 4);
        sh0_s[t] = s4.x;
        shv_s[t][0] = s4.y; shv_s[t][1] = s4.z; shv_s[t][2] = s4.w;
    }
    {   // gather node features: 2 threads/edge, 10 float4 each -> bf16 xs/xv
        const int e = t >> 1, q = t & 1;
        const int src = ei[e0 + e];
        const float* p = nf + (size_t)src * 80 + q * 40;
        #pragma unroll
        for (int f4 = 0; f4 < 10; f4++) {
            const float4 v = *reinterpret_cast<const float4*>(p + f4 * 4);
            const int g = q * 40 + f4 * 4;
            const float vv[4] = {v.x, v.y, v.z, v.w};
            #pragma unroll
            for (int ii = 0; ii < 4; ii++) {
                const int gg = g + ii;
                if (gg < 32) xs_s[e][gg]      = f2bf(vv[ii]);
                else         xv_s[e][gg - 32] = f2bf(vv[ii]);
            }
        }
    }
    for (int i = t; i < 512;  i += 256) rW1_s[i] = rW1[i];
    for (int i = t; i < 2304; i += 256) rb2_s[i] = rb2[i];
    __syncthreads();            // xs/xv/sh/rW1 ready

    // --- prologue part 2: dv + per-lane radial h -> register b-frags ---
    {   // dv[e][u] from bf16 xv (2 threads/edge, 8 u each)
        const int e = t >> 1, u0d = (t & 1) * 8;
        #pragma unroll
        for (int i = 0; i < 8; i++) {
            const int u = u0d + i;
            dv_s[e][u] = bf2f(xv_s[e][u*3+0]) * shv_s[e][0]
                       + bf2f(xv_s[e][u*3+1]) * shv_s[e][1]
                       + bf2f(xv_s[e][u*3+2]) * shv_s[e][2];
        }
    }
    const int eA = wv * 32 + l15;           // this lane's n-tile0 edge (block-local)
    const int eB = eA + 16;                 // n-tile1 edge
    short8 bfr[2][2];                       // [ntile][s] h fragments
    {
        float embA[8], embB[8];
        {
            const float* pa = emb + (size_t)(e0 + eA) * 8;
            const float* pb = emb + (size_t)(e0 + eB) * 8;
            const float4 a0 = *reinterpret_cast<const float4*>(pa);
            const float4 a1 = *reinterpret_cast<const float4*>(pa + 4);
            const float4 b0 = *reinterpret_cast<const float4*>(pb);
            const float4 b1 = *reinterpret_cast<const float4*>(pb + 4);
            embA[0]=a0.x; embA[1]=a0.y; embA[2]=a0.z; embA[3]=a0.w;
            embA[4]=a1.x; embA[5]=a1.y; embA[6]=a1.z; embA[7]=a1.w;
            embB[0]=b0.x; embB[1]=b0.y; embB[2]=b0.z; embB[3]=b0.w;
            embB[4]=b1.x; embB[5]=b1.y; embB[6]=b1.z; embB[7]=b1.w;
        }
        #pragma unroll
        for (int s = 0; s < 2; s++) {
            const int k0 = s * 32 + lk * 8;
            const float4 r0 = *reinterpret_cast<const float4*>(rb1 + k0);
            const float4 r1 = *reinterpret_cast<const float4*>(rb1 + k0 + 4);
            float preA[8] = {r0.x,r0.y,r0.z,r0.w, r1.x,r1.y,r1.z,r1.w};
            float preB[8] = {r0.x,r0.y,r0.z,r0.w, r1.x,r1.y,r1.z,r1.w};
            #pragma unroll
            for (int b = 0; b < 8; b++) {
                const float4 wa = *reinterpret_cast<const float4*>(&rW1_s[b * 64 + k0]);
                const float4 wb = *reinterpret_cast<const float4*>(&rW1_s[b * 64 + k0 + 4]);
                const float wv4[8] = {wa.x,wa.y,wa.z,wa.w, wb.x,wb.y,wb.z,wb.w};
                #pragma unroll
                for (int j = 0; j < 8; j++) {
                    preA[j] = fmaf(embA[b], wv4[j], preA[j]);
                    preB[j] = fmaf(embB[b], wv4[j], preB[j]);
                }
            }
            short8 hA, hBv;
            #pragma unroll
            for (int j = 0; j < 8; j++) {
                hA[j]  = (short)f2bf(silu_f(preA[j]));
                hBv[j] = (short)f2bf(silu_f(preB[j]));
            }
            bfr[0][s] = hA; bfr[1][s] = hBv;
        }
    }
    const float sh0A = sh0_s[eA], sh0B = sh0_s[eB];
    const float fAA  = PW0_C * sh0A, fAB = PW0_C * sh0B;
    __syncthreads();            // dv ready

    // message accumulators, per owned edge
    float sA0[2][4] = {{0,0,0,0},{0,0,0,0}}, sA1[2][4] = {{0,0,0,0},{0,0,0,0}};
    float sB0[4] = {0,0,0,0},                sB1[4] = {0,0,0,0};
    float sC0[3][4] = {{0,0,0,0},{0,0,0,0},{0,0,0,0}};
    float sC1[3][4] = {{0,0,0,0},{0,0,0,0},{0,0,0,0}};

    // Load chunk cc's 8 A-fragments (2 k-halves x 4 m-tiles) from L2 into regs.
    #define LOADA(cc, dst) {                                                      \
        const int cb_ = (cc) * 64;                                                \
        _Pragma("unroll")                                                         \
        for (int s = 0; s < 2; s++)                                               \
            _Pragma("unroll")                                                     \
            for (int m = 0; m < 4; m++)                                           \
                dst[s * 4 + m] = *reinterpret_cast<const short8*>(                \
                    rW2T + (size_t)(cb_ + m * 16 + l15) * 64 + s * 32 + lk * 8);  \
    }

    // 16 MFMAs from register A-frags (bias-initialized acc)
    #define GEMMR(cc, af, a0, a1) {                                               \
        const int cb_ = (cc) * 64;                                                \
        _Pragma("unroll")                                                         \
        for (int m = 0; m < 4; m++) {                                             \
            const float4 rbv = *reinterpret_cast<const float4*>(                  \
                &rb2_s[cb_ + m * 16 + lk * 4]);                                   \
            a0[m][0] = rbv.x; a0[m][1] = rbv.y; a0[m][2] = rbv.z; a0[m][3] = rbv.w; \
            a1[m][0] = rbv.x; a1[m][1] = rbv.y; a1[m][2] = rbv.z; a1[m][3] = rbv.w; \
        }                                                                         \
        _Pragma("unroll")                                                         \
        for (int s = 0; s < 2; s++) {                                             \
            _Pragma("unroll")                                                     \
            for (int m = 0; m < 4; m++) {                                         \
                a0[m] = __builtin_amdgcn_mfma_f32_16x16x32_bf16(af[s*4+m], bfr[0][s], a0[m], 0, 0, 0); \
                a1[m] = __builtin_amdgcn_mfma_f32_16x16x32_bf16(af[s*4+m], bfr[1][s], a1[m], 0, 0, 0); \
            }                                                                     \
        } }

    #define EPI(cc, a0, a1) {                                                     \
        const int c_ = (cc);                                                      \
        if (c_ < 16) {                                                            \
            const float xA0 = bf2f(xs_s[eA][c_*2]) * fAA, xA1 = bf2f(xs_s[eA][c_*2+1]) * fAA; \
            const float xB0 = bf2f(xs_s[eB][c_*2]) * fAB, xB1 = bf2f(xs_s[eB][c_*2+1]) * fAB; \
            _Pragma("unroll")                                                     \
            for (int r = 0; r < 4; r++) {                                         \
                sA0[0][r] = fmaf(a0[0][r], xA0, fmaf(a0[2][r], xA1, sA0[0][r]));  \
                sA0[1][r] = fmaf(a0[1][r], xA0, fmaf(a0[3][r], xA1, sA0[1][r]));  \
                sA1[0][r] = fmaf(a1[0][r], xB0, fmaf(a1[2][r], xB1, sA1[0][r]));  \
                sA1[1][r] = fmaf(a1[1][r], xB0, fmaf(a1[3][r], xB1, sA1[1][r]));  \
            }                                                                     \
        } else if (c_ < 24) {                                                     \
            const int u0 = (c_ - 16) * 4;                                         \
            float xA[4], xB[4];                                                   \
            _Pragma("unroll")                                                     \
            for (int m = 0; m < 4; m++) { xA[m] = bf2f(xs_s[eA][u0+m]); xB[m] = bf2f(xs_s[eB][u0+m]); } \
            _Pragma("unroll")                                                     \
            for (int r = 0; r < 4; r++) {                                         \
                sB0[r] = fmaf(a0[0][r], xA[0], fmaf(a0[1][r], xA[1],              \
                          fmaf(a0[2][r], xA[2], fmaf(a0[3][r], xA[3], sB0[r])))); \
                sB1[r] = fmaf(a1[0][r], xB[0], fmaf(a1[1][r], xB[1],              \
                          fmaf(a1[2][r], xB[2], fmaf(a1[3][r], xB[3], sB1[r])))); \
            }                                                                     \
        } else if (c_ < 28) {                                                     \
            const int u0 = (c_ - 24) * 4;                                         \
            _Pragma("unroll")                                                     \
            for (int k = 0; k < 3; k++) {                                         \
                float xA[4], xB[4];                                               \
                _Pragma("unroll")                                                 \
                for (int m = 0; m < 4; m++) {                                     \
                    xA[m] = bf2f(xv_s[eA][(u0+m)*3+k]);                           \
                    xB[m] = bf2f(xv_s[eB][(u0+m)*3+k]);                           \
                }                                                                 \
                _Pragma("unroll")                                                 \
                for (int r = 0; r < 4; r++) {                                     \
                    sC0[k][r] = fmaf(a0[0][r], xA[0], fmaf(a0[1][r], xA[1],       \
                                 fmaf(a0[2][r], xA[2], fmaf(a0[3][r], xA[3], sC0[k][r])))); \
                    sC1[k][r] = fmaf(a1[0][r], xB[0], fmaf(a1[1][r], xB[1],       \
                                 fmaf(a1[2][r], xB[2], fmaf(a1[3][r], xB[3], sC1[k][r])))); \
                }                                                                 \
            }                                                                     \
        } else {                                                                  \
            const int u0 = (c_ - 28) * 2;                                         \
            const float dA0 = dv_s[eA][u0] * PW0IS3_C, dA1 = dv_s[eA][u0+1] * PW0IS3_C; \
            const float dB0 = dv_s[eB][u0] * PW0IS3_C, dB1 = dv_s[eB][u0+1] * PW0IS3_C; \
            _Pragma("unroll")                                                     \
            for (int r = 0; r < 4; r++) {                                         \
                sA0[0][r] = fmaf(a0[0][r], dA0, fmaf(a0[2][r], dA1, sA0[0][r]));  \
                sA0[1][r] = fmaf(a0[1][r], dA0, fmaf(a0[3][r], dA1, sA0[1][r]));  \
                sA1[0][r] = fmaf(a1[0][r], dB0, fmaf(a1[2][r], dB1, sA1[0][r]));  \
                sA1[1][r] = fmaf(a1[1][r], dB0, fmaf(a1[3][r], dB1, sA1[1][r]));  \
            }                                                                     \
        } }

    // --- main loop: BARRIER-FREE, unroll-by-2, depth-1 register prefetch ---
    // afA holds even chunks, afB odd chunks; loads for chunk c+1 issued before
    // chunk c's MFMAs -> ~1 chunk of compute hides the L2 latency.
    short8 afA[8], afB[8];
    LOADA(0, afA)
    for (int c = 0; c < 36; c += 2) {
        if (c + 1 < 36) LOADA(c + 1, afB)
        {
            f32x4 a0[4], a1[4];
            GEMMR(c, afA, a0, a1)
            EPI(c, a0, a1)
        }
        if (c + 2 < 36) LOADA(c + 2, afA)
        {
            f32x4 a0[4], a1[4];
            GEMMR(c + 1, afB, a0, a1)
            EPI(c + 1, a0, a1)
        }
    }
    #undef LOADA
    #undef GEMMR
    #undef EPI

    // --- scatter in 2 passes of 64 edges (msg is its own LDS array) ---
    #pragma unroll
    for (int pass = 0; pass < 2; ++pass) {
        __syncthreads();                    // previous pass reads done
        if ((wv >> 1) == pass) {
            const int lr0 = (wv & 1) * 32 + l15;   // local rows within this pass
            const int lr1 = lr0 + 16;
            #pragma unroll
            for (int hi = 0; hi < 2; hi++)
                #pragma unroll
                for (int r = 0; r < 4; r++) {
                    msg[lr0][hi * 16 + lk * 4 + r] = sA0[hi][r];
                    msg[lr1][hi * 16 + lk * 4 + r] = sA1[hi][r];
                }
            #pragma unroll
            for (int r = 0; r < 4; r++) {
                const int w = lk * 4 + r;
                #pragma unroll
                for (int k = 0; k < 3; k++) {
                    msg[lr0][32 + w * 3 + k] = C1_C * (sB0[r] * shv_s[eA][k] + sh0A * sC0[k][r]);
                    msg[lr1][32 + w * 3 + k] = C1_C * (sB1[r] * shv_s[eB][k] + sh0B * sC1[k][r]);
                }
            }
        }
        __syncthreads();                    // msg tile ready
        const int ebase = pass * 64;
        for (int i = t; i < 64 * 80; i += 256) {
            const int rr = i / 80, m = i - rr * 80;
            atomicAdd(&agg[(size_t)dst_s[ebase + rr] * 80 + m], msg[rr][m]);
        }
    }
}

// ---------------- fallback f32 edge kernel (proven R3) ----------------
__global__ __launch_bounds__(256, 1) void edge_kernel_f32(
    const float* __restrict__ nf, const int* __restrict__ ei,
    const float* __restrict__ sh, const float* __restrict__ emb,
    const float* __restrict__ rW1, const float* __restrict__ rb1,
    const float* __restrict__ rW2, const float* __restrict__ rb2,
    float* __restrict__ agg)
{
    __shared__ float hT[64][68];
    __shared__ float tpw[64][132];
    __shared__ float xs_s[64][32];
    __shared__ float xv_s[64][48];
    __shared__ float dv_s[64][16];
    __shared__ float sh0_s[64];
    __shared__ float shv_s[64][3];
    __shared__ int   dst_s[64];
    __shared__ float msg[64][84];

    const int t  = threadIdx.x;
    const int e0 = blockIdx.x * 64;
    if (t < 64) {
        const int eid = e0 + t;
        dst_s[t] = ei[N_EDGES_C + eid];
        const float4 s4 = *reinterpret_cast<const float4*>(sh + (size_t)eid * 4);
        sh0_s[t] = s4.x; shv_s[t][0] = s4.y; shv_s[t][1] = s4.z; shv_s[t][2] = s4.w;
    }
    for (int i = t; i < 64 * 84; i += 256) (&msg[0][0])[i] = 0.0f;
    {
        const int e = t >> 2, q = t & 3;
        const int src = ei[e0 + e];
        const float* p = nf + (size_t)src * 80 + q * 20;
        #pragma unroll
        for (int f4 = 0; f4 < 5; f4++) {
            const float4 v = *reinterpret_cast<const float4*>(p + f4 * 4);
            const int g = q * 20 + f4 * 4;
            const float vv[4] = {v.x, v.y, v.z, v.w};
            #pragma unroll
            for (int ii = 0; ii < 4; ii++) {
                const int gg = g + ii;
                if (gg < 32) xs_s[e][gg] = vv[ii]; else xv_s[e][gg - 32] = vv[ii];
            }
        }
    }
    {
        const int c = t & 63, eg = t >> 6;
        float w1[8];
        #pragma unroll
        for (int b = 0; b < 8; b++) w1[b] = rW1[b * 64 + c];
        const float bias = rb1[c];
        #pragma unroll
        for (int rep = 0; rep < 16; rep++) {
            const int e = rep * 4 + eg;
            const float* em = emb + (size_t)(e0 + e) * 8;
            float pre = bias;
            #pragma unroll
            for (int b = 0; b < 8; b++) pre = fmaf(em[b], w1[b], pre);
            hT[c][e] = silu_f(pre);
        }
    }
    __syncthreads();
    {
        const int e = t >> 2, q = t & 3;
        #pragma unroll
        for (int i = 0; i < 4; i++) {
            const int u = q * 4 + i;
            dv_s[e][u] = xv_s[e][u*3+0]*shv_s[e][0] + xv_s[e][u*3+1]*shv_s[e][1]
                       + xv_s[e][u*3+2]*shv_s[e][2];
        }
    }
    __syncthreads();
    const int lane = t & 63, wv = t >> 6;
    for (int ch = 0; ch < 18; ch++) {
        const int jb = ch * 128;
        float acc[16][2];
        #pragma unroll
        for (int i = 0; i < 16; i++) { acc[i][0] = 0.0f; acc[i][1] = 0.0f; }
        const float* Bp = rW2 + jb + lane * 2;
        #pragma unroll 2
        for (int c = 0; c < 64; c++) {
            const float2 b = *reinterpret_cast<const float2*>(Bp + (size_t)c * 2304);
            const float4* ap = reinterpret_cast<const float4*>(&hT[c][wv * 16]);
            const float4 a0 = ap[0], a1 = ap[1], a2 = ap[2], a3 = ap[3];
            const float va[16] = {a0.x,a0.y,a0.z,a0.w, a1.x,a1.y,a1.z,a1.w,
                                  a2.x,a2.y,a2.z,a2.w, a3.x,a3.y,a3.z,a3.w};
            #pragma unroll
            for (int i = 0; i < 16; i++) {
                acc[i][0] = fmaf(va[i], b.x, acc[i][0]);
                acc[i][1] = fmaf(va[i], b.y, acc[i][1]);
            }
        }
        const float2 rb = *reinterpret_cast<const float2*>(rb2 + jb + lane * 2);
        __syncthreads();
        #pragma unroll
        for (int i = 0; i < 16; i++)
            *reinterpret_cast<float2*>(&tpw[wv * 16 + i][lane * 2]) =
                make_float2(acc[i][0] + rb.x, acc[i][1] + rb.y);
        __syncthreads();
        if (ch < 8) {
            const int u0 = ch * 4, w = t & 31, eg = t >> 5;
            #pragma unroll
            for (int ee = 0; ee < 8; ee++) {
                const int e = eg * 8 + ee;
                float s = 0.0f;
                #pragma unroll
                for (int du = 0; du < 4; du++) s = fmaf(tpw[e][du * 32 + w], xs_s[e][u0 + du], s);
                msg[e][w] = fmaf(PW0_C * sh0_s[e], s, msg[e][w]);
            }
        } else if (ch < 12) {
            const int u0 = (ch - 8) * 8, w = t & 15, eg = t >> 4;
            #pragma unroll
            for (int ee = 0; ee < 4; ee++) {
                const int e = eg * 4 + ee;
                float s = 0.0f;
                #pragma unroll
                for (int du = 0; du < 8; du++) s = fmaf(tpw[e][du * 16 + w], xs_s[e][u0 + du], s);
                const float c1s = C1_C * s;
                msg[e][32 + w*3 + 0] = fmaf(c1s, shv_s[e][0], msg[e][32 + w*3 + 0]);
                msg[e][32 + w*3 + 1] = fmaf(c1s, shv_s[e][1], msg[e][32 + w*3 + 1]);
                msg[e][32 + w*3 + 2] = fmaf(c1s, shv_s[e][2], msg[e][32 + w*3 + 2]);
            }
        } else if (ch < 14) {
            const int u0 = (ch - 12) * 8, w = t & 15, eg = t >> 4;
            #pragma unroll
            for (int ee = 0; ee < 4; ee++) {
                const int e = eg * 4 + ee;
                float s0 = 0, s1 = 0, s2 = 0;
                #pragma unroll
                for (int du = 0; du < 8; du++) {
                    const float tv = tpw[e][du * 16 + w];
                    const int u = u0 + du;
                    s0 = fmaf(tv, xv_s[e][u*3 + 0], s0);
                    s1 = fmaf(tv, xv_s[e][u*3 + 1], s1);
                    s2 = fmaf(tv, xv_s[e][u*3 + 2], s2);
                }
                const float f = C1_C * sh0_s[e];
                msg[e][32 + w*3 + 0] = fmaf(f, s0, msg[e][32 + w*3 + 0]);
                msg[e][32 + w*3 + 1] = fmaf(f, s1, msg[e][32 + w*3 + 1]);
                msg[e][32 + w*3 + 2] = fmaf(f, s2, msg[e][32 + w*3 + 2]);
            }
        } else {
            const int u0 = (ch - 14) * 4, w = t & 31, eg = t >> 5;
            #pragma unroll
            for (int ee = 0; ee < 8; ee++) {
                const int e = eg * 8 + ee;
                float s = 0.0f;
                #pragma unroll
                for (int du = 0; du < 4; du++) s = fmaf(tpw[e][du * 32 + w], dv_s[e][u0 + du], s);
                msg[e][w] = fmaf(PW0IS3_C, s, msg[e][w]);
            }
        }
    }
    __syncthreads();
    for (int i = t; i < 64 * 80; i += 256) {
        const int e = i / 80, m = i - e * 80;
        atomicAdd(&agg[(size_t)dst_s[e] * 80 + m], msg[e][m]);
    }
}

// Node update, IN PLACE on io (= d_out, holding agg).
__global__ __launch_bounds__(256, 4) void node_kernel(
    const float* __restrict__ nf,
    float* __restrict__ io,
    const float* __restrict__ Wl0,
    const float* __restrict__ Wl1)
{
    __shared__ float a_s[4][80];
    const int t  = threadIdx.x;
    const int nb = blockIdx.x * 4;
    for (int i = t; i < 320; i += 256)
        a_s[i / 80][i % 80] = io[(size_t)nb * 80 + i];
    __syncthreads();

    const int ln = t >> 6;
    const int r  = t & 63;
    const int n  = nb + ln;
    const float* a = a_s[ln];
    if (r < 32) {
        float s = 0.0f;
        #pragma unroll
        for (int u = 0; u < 32; u++) s = fmaf(a[u], Wl0[u * 32 + r], s);
        s *= RS32_C;
        io[(size_t)n * 80 + r] = nf[(size_t)n * 80 + r] + silu_f(s);
    } else if (r < 48) {
        const int v = r - 32;
        float l0 = 0, l1 = 0, l2 = 0;
        #pragma unroll
        for (int u = 0; u < 16; u++) {
            const float w = Wl1[u * 16 + v];
            l0 = fmaf(a[32 + u*3 + 0], w, l0);
            l1 = fmaf(a[32 + u*3 + 1], w, l1);
            l2 = fmaf(a[32 + u*3 + 2], w, l2);
        }
        l0 *= 0.25f; l1 *= 0.25f; l2 *= 0.25f;
        const float norm = sqrtf(l0*l0 + l1*l1 + l2*l2);
        float f = 0.0f;
        if (norm >= 1e-8f) f = silu_f(norm) / norm;
        const size_t o = (size_t)n * 80 + 32 + (size_t)v * 3;
        io[o + 0] = nf[o + 0] + f * l0;
        io[o + 1] = nf[o + 1] + f * l1;
        io[o + 2] = nf[o + 2] + f * l2;
    }
}

extern "C" void kernel_launch(void* const* d_in, const int* in_sizes, int n_in,
                              void* d_out, int out_size, void* d_ws, size_t ws_size,
                              hipStream_t stream) {
    const float* nf  = (const float*)d_in[0];
    const int*   ei  = (const int*)d_in[1];
    const float* sh  = (const float*)d_in[2];
    const float* emb = (const float*)d_in[3];
    const float* rW1 = (const float*)d_in[4];
    const float* rb1 = (const float*)d_in[5];
    const float* rW2 = (const float*)d_in[6];
    const float* rb2 = (const float*)d_in[7];
    const float* Wl0 = (const float*)d_in[8];
    const float* Wl1 = (const float*)d_in[9];

    float* agg = (float*)d_out;
    hipMemsetAsync(agg, 0, (size_t)N_NODES_C * 80 * sizeof(float), stream);

    const size_t rW2T_bytes = (size_t)2304 * 64 * sizeof(unsigned short);
    if (d_ws != nullptr && ws_size >= rW2T_bytes) {
        unsigned short* rW2T = (unsigned short*)d_ws;
        prep_kernel<<<(2304 * 64) / 256, 256, 0, stream>>>(rW2, rW2T);
        edge_kernel_mfma<<<N_EDGES_C / 128, 256, 0, stream>>>(
            nf, ei, sh, emb, rW1, rb1, rW2T, rb2, agg);
    } else {
        edge_kernel_f32<<<N_EDGES_C / 64, 256, 0, stream>>>(
            nf, ei, sh, emb, rW1, rb1, rW2, rb2, agg);
    }
    node_kernel<<<N_NODES_C / 4, 256, 0, stream>>>(nf, agg, Wl0, Wl1);
}

// Round 16
// 64.069 us; speedup vs baseline: 1.6322x; 1.6322x over previous
//
#include <hip/hip_runtime.h>
#include <math.h>

#define N_NODES_C 8000
#define N_EDGES_C 64000

static constexpr float PW0_C     = 0.14433756729740646f;   // sqrt(1/48)
static constexpr float C1_C      = 0.14433756729740643f;   // PW1 * INV_SQRT3
static constexpr float PW0IS3_C  = 0.08333333333333333f;   // PW0 * INV_SQRT3
static constexpr float RS32_C    = 0.17677669529663687f;   // 1/sqrt(32)

typedef __attribute__((ext_vector_type(8))) short short8;
typedef __attribute__((ext_vector_type(4))) float f32x4;

__device__ __forceinline__ float silu_f(float x) { return x / (1.0f + expf(-x)); }

__device__ __forceinline__ unsigned short f2bf(float x) {
    union { float f; unsigned u; } a; a.f = x;
    unsigned r = a.u + 0x7fffu + ((a.u >> 16) & 1u);   // RNE
    return (unsigned short)(r >> 16);
}
__device__ __forceinline__ float bf2f(unsigned short x) {
    union { unsigned u; float f; } a; a.u = ((unsigned)x) << 16; return a.f;
}

__device__ __forceinline__ void stage16(const void* g, void* lds) {
    __builtin_amdgcn_global_load_lds(
        (const __attribute__((address_space(1))) void*)g,
        (__attribute__((address_space(3))) void*)lds, 16, 0, 0);
}

// Transpose rW2 (64 x 2304 f32) -> rW2T (2304 x 64 bf16). Coalesced reads.
__global__ __launch_bounds__(256) void prep_kernel(
    const float* __restrict__ rW2, unsigned short* __restrict__ rW2T)
{
    const int idx = blockIdx.x * 256 + threadIdx.x;
    const int k = idx / 2304, col = idx % 2304;
    rW2T[(size_t)col * 64 + k] = f2bf(rW2[idx]);
}

// MFMA edge kernel: 128 edges/block, 4 waves x 2 n-tiles (32 edges/wave).
// R11 (best proven): 2 chunks per barrier window (18 pair-iterations),
// stage-after-barrier 2-pair-buffer ledger, counted vmcnt, raw barrier.
__global__ __launch_bounds__(256, 2) void edge_kernel_mfma(
    const float* __restrict__ nf,
    const int*   __restrict__ ei,
    const float* __restrict__ sh,
    const float* __restrict__ emb,
    const float* __restrict__ rW1,
    const float* __restrict__ rb1,
    const unsigned short* __restrict__ rW2T,
    const float* __restrict__ rb2,
    float* __restrict__ agg)
{
    __shared__ float pool_f[8192];          // 32KB: 2 pair-bufs x 16KB; msg[64][84] aliases after loop
    __shared__ float rb2_s[2304];           // 9.2KB
    __shared__ float rW1_s[512];            // 2KB  [b*64+k]
    __shared__ unsigned short xs_s[128][34];// 8.7KB bf16
    __shared__ unsigned short xv_s[128][50];// 12.8KB bf16
    __shared__ float dv_s[128][17];         // 8.7KB
    __shared__ float sh0_s[128];
    __shared__ float shv_s[128][3];
    __shared__ int   dst_s[128];

    char*  stg = (char*)pool_f;
    float (*msg)[84] = reinterpret_cast<float(*)[84]>(pool_f);

    const int t    = threadIdx.x;
    const int e0   = blockIdx.x * 128;
    const int lane = t & 63, wv = t >> 6;
    const int l15  = lane & 15, lk = lane >> 4;
    const int l7   = l15 & 7;

    // stage PAIR pp (chunks 2pp,2pp+1; 16KB) into pair-buffer b; swizzled source.
    #define STAGEPAIR(pp, b) {                                                    \
        const char* gsrc = (const char*)rW2T + (size_t)(pp) * 16384;              \
        _Pragma("unroll")                                                         \
        for (int j = 0; j < 4; j++) {                                             \
            const int p_ = j * 256 + t;                                           \
            const int pr = p_ >> 3;                                               \
            const int sl = (p_ & 7) ^ (pr & 7);                                   \
            stage16(gsrc + pr * 128 + (sl << 4), stg + (b) * 16384 + p_ * 16);    \
        }                                                                         \
    }

    // --- prologue part 1 ---
    STAGEPAIR(0, 0)                          // chunks 0,1 into pair-buf 0
    if (t < 128) {
        const int eid = e0 + t;
        dst_s[t] = ei[N_EDGES_C + eid];
        const float4 s4 = *reinterpret_cast<const float4*>(sh + (size_t)eid * 4);
        sh0_s[t] = s4.x;
        shv_s[t][0] = s4.y; shv_s[t][1] = s4.z; shv_s[t][2] = s4.w;
    }
    {   // gather node features: 2 threads/edge, 10 float4 each -> bf16 xs/xv
        const int e = t >> 1, q = t & 1;
        const int src = ei[e0 + e];
        const float* p = nf + (size_t)src * 80 + q * 40;
        #pragma unroll
        for (int f4 = 0; f4 < 10; f4++) {
            const float4 v = *reinterpret_cast<const float4*>(p + f4 * 4);
            const int g = q * 40 + f4 * 4;
            const float vv[4] = {v.x, v.y, v.z, v.w};
            #pragma unroll
            for (int ii = 0; ii < 4; ii++) {
                const int gg = g + ii;
                if (gg < 32) xs_s[e][gg]      = f2bf(vv[ii]);
                else         xv_s[e][gg - 32] = f2bf(vv[ii]);
            }
        }
    }
    for (int i = t; i < 512;  i += 256) rW1_s[i] = rW1[i];
    for (int i = t; i < 2304; i += 256) rb2_s[i] = rb2[i];
    __syncthreads();            // xs/xv/sh/rW1 ready; drains STAGEPAIR(0) too

    // --- prologue part 2: dv + per-lane radial h -> register b-frags ---
    {   // dv[e][u] from bf16 xv (2 threads/edge, 8 u each)
        const int e = t >> 1, u0d = (t & 1) * 8;
        #pragma unroll
        for (int i = 0; i < 8; i++) {
            const int u = u0d + i;
            dv_s[e][u] = bf2f(xv_s[e][u*3+0]) * shv_s[e][0]
                       + bf2f(xv_s[e][u*3+1]) * shv_s[e][1]
                       + bf2f(xv_s[e][u*3+2]) * shv_s[e][2];
        }
    }
    const int eA = wv * 32 + l15;           // this lane's n-tile0 edge (block-local)
    const int eB = eA + 16;                 // n-tile1 edge
    short8 bfr[2][2];                       // [ntile][s] h fragments
    {
        float embA[8], embB[8];
        {
            const float* pa = emb + (size_t)(e0 + eA) * 8;
            const float* pb = emb + (size_t)(e0 + eB) * 8;
            const float4 a0 = *reinterpret_cast<const float4*>(pa);
            const float4 a1 = *reinterpret_cast<const float4*>(pa + 4);
            const float4 b0 = *reinterpret_cast<const float4*>(pb);
            const float4 b1 = *reinterpret_cast<const float4*>(pb + 4);
            embA[0]=a0.x; embA[1]=a0.y; embA[2]=a0.z; embA[3]=a0.w;
            embA[4]=a1.x; embA[5]=a1.y; embA[6]=a1.z; embA[7]=a1.w;
            embB[0]=b0.x; embB[1]=b0.y; embB[2]=b0.z; embB[3]=b0.w;
            embB[4]=b1.x; embB[5]=b1.y; embB[6]=b1.z; embB[7]=b1.w;
        }
        #pragma unroll
        for (int s = 0; s < 2; s++) {
            const int k0 = s * 32 + lk * 8;
            const float4 r0 = *reinterpret_cast<const float4*>(rb1 + k0);
            const float4 r1 = *reinterpret_cast<const float4*>(rb1 + k0 + 4);
            float preA[8] = {r0.x,r0.y,r0.z,r0.w, r1.x,r1.y,r1.z,r1.w};
            float preB[8] = {r0.x,r0.y,r0.z,r0.w, r1.x,r1.y,r1.z,r1.w};
            #pragma unroll
            for (int b = 0; b < 8; b++) {
                const float4 wa = *reinterpret_cast<const float4*>(&rW1_s[b * 64 + k0]);
                const float4 wb = *reinterpret_cast<const float4*>(&rW1_s[b * 64 + k0 + 4]);
                const float wv4[8] = {wa.x,wa.y,wa.z,wa.w, wb.x,wb.y,wb.z,wb.w};
                #pragma unroll
                for (int j = 0; j < 8; j++) {
                    preA[j] = fmaf(embA[b], wv4[j], preA[j]);
                    preB[j] = fmaf(embB[b], wv4[j], preB[j]);
                }
            }
            short8 hA, hBv;
            #pragma unroll
            for (int j = 0; j < 8; j++) {
                hA[j]  = (short)f2bf(silu_f(preA[j]));
                hBv[j] = (short)f2bf(silu_f(preB[j]));
            }
            bfr[0][s] = hA; bfr[1][s] = hBv;
        }
    }
    const float sh0A = sh0_s[eA], sh0B = sh0_s[eB];
    const float fAA  = PW0_C * sh0A, fAB = PW0_C * sh0B;
    __syncthreads();            // dv ready; loop may start

    // message accumulators, per owned edge
    float sA0[2][4] = {{0,0,0,0},{0,0,0,0}}, sA1[2][4] = {{0,0,0,0},{0,0,0,0}};
    float sB0[4] = {0,0,0,0},                sB1[4] = {0,0,0,0};
    float sC0[3][4] = {{0,0,0,0},{0,0,0,0},{0,0,0,0}};
    float sC1[3][4] = {{0,0,0,0},{0,0,0,0},{0,0,0,0}};

    // GEMM for chunk cc into acc pair. Chunk cc lives at pair-buf[(cc>>1)&1],
    // half (cc&1).
    #define GEMM2(cc, a0, a1) {                                                   \
        const int cb_ = (cc) * 64;                                                \
        const char* sb_ = stg + (((cc) >> 1) & 1) * 16384 + ((cc) & 1) * 8192;    \
        _Pragma("unroll")                                                         \
        for (int m = 0; m < 4; m++) {                                             \
            const float4 rbv = *reinterpret_cast<const float4*>(                  \
                &rb2_s[cb_ + m * 16 + lk * 4]);                                   \
            a0[m][0] = rbv.x; a0[m][1] = rbv.y; a0[m][2] = rbv.z; a0[m][3] = rbv.w; \
            a1[m][0] = rbv.x; a1[m][1] = rbv.y; a1[m][2] = rbv.z; a1[m][3] = rbv.w; \
        }                                                                         \
        _Pragma("unroll")                                                         \
        for (int s = 0; s < 2; s++) {                                             \
            _Pragma("unroll")                                                     \
            for (int m = 0; m < 4; m++) {                                         \
                const short8 a_ = *reinterpret_cast<const short8*>(               \
                    sb_ + (m * 16 + l15) * 128 + (((s * 4 + lk) ^ l7) << 4));     \
                a0[m] = __builtin_amdgcn_mfma_f32_16x16x32_bf16(a_, bfr[0][s], a0[m], 0, 0, 0); \
                a1[m] = __builtin_amdgcn_mfma_f32_16x16x32_bf16(a_, bfr[1][s], a1[m], 0, 0, 0); \
            }                                                                     \
        } }

    // Epilogue for chunk cc consuming acc pair (uniform runtime branch)
    #define EPI(cc, a0, a1) {                                                     \
        const int c_ = (cc);                                                      \
        if (c_ < 16) {                                                            \
            const float xA0 = bf2f(xs_s[eA][c_*2]) * fAA, xA1 = bf2f(xs_s[eA][c_*2+1]) * fAA; \
            const float xB0 = bf2f(xs_s[eB][c_*2]) * fAB, xB1 = bf2f(xs_s[eB][c_*2+1]) * fAB; \
            _Pragma("unroll")                                                     \
            for (int r = 0; r < 4; r++) {                                         \
                sA0[0][r] = fmaf(a0[0][r], xA0, fmaf(a0[2][r], xA1, sA0[0][r]));  \
                sA0[1][r] = fmaf(a0[1][r], xA0, fmaf(a0[3][r], xA1, sA0[1][r]));  \
                sA1[0][r] = fmaf(a1[0][r], xB0, fmaf(a1[2][r], xB1, sA1[0][r]));  \
                sA1[1][r] = fmaf(a1[1][r], xB0, fmaf(a1[3][r], xB1, sA1[1][r]));  \
            }                                                                     \
        } else if (c_ < 24) {                                                     \
            const int u0 = (c_ - 16) * 4;                                         \
            float xA[4], xB[4];                                                   \
            _Pragma("unroll")                                                     \
            for (int m = 0; m < 4; m++) { xA[m] = bf2f(xs_s[eA][u0+m]); xB[m] = bf2f(xs_s[eB][u0+m]); } \
            _Pragma("unroll")                                                     \
            for (int r = 0; r < 4; r++) {                                         \
                sB0[r] = fmaf(a0[0][r], xA[0], fmaf(a0[1][r], xA[1],              \
                          fmaf(a0[2][r], xA[2], fmaf(a0[3][r], xA[3], sB0[r])))); \
                sB1[r] = fmaf(a1[0][r], xB[0], fmaf(a1[1][r], xB[1],              \
                          fmaf(a1[2][r], xB[2], fmaf(a1[3][r], xB[3], sB1[r])))); \
            }                                                                     \
        } else if (c_ < 28) {                                                     \
            const int u0 = (c_ - 24) * 4;                                         \
            _Pragma("unroll")                                                     \
            for (int k = 0; k < 3; k++) {                                         \
                float xA[4], xB[4];                                               \
                _Pragma("unroll")                                                 \
                for (int m = 0; m < 4; m++) {                                     \
                    xA[m] = bf2f(xv_s[eA][(u0+m)*3+k]);                           \
                    xB[m] = bf2f(xv_s[eB][(u0+m)*3+k]);                           \
                }                                                                 \
                _Pragma("unroll")                                                 \
                for (int r = 0; r < 4; r++) {                                     \
                    sC0[k][r] = fmaf(a0[0][r], xA[0], fmaf(a0[1][r], xA[1],       \
                                 fmaf(a0[2][r], xA[2], fmaf(a0[3][r], xA[3], sC0[k][r])))); \
                    sC1[k][r] = fmaf(a1[0][r], xB[0], fmaf(a1[1][r], xB[1],       \
                                 fmaf(a1[2][r], xB[2], fmaf(a1[3][r], xB[3], sC1[k][r])))); \
                }                                                                 \
            }                                                                     \
        } else {                                                                  \
            const int u0 = (c_ - 28) * 2;                                         \
            const float dA0 = dv_s[eA][u0] * PW0IS3_C, dA1 = dv_s[eA][u0+1] * PW0IS3_C; \
            const float dB0 = dv_s[eB][u0] * PW0IS3_C, dB1 = dv_s[eB][u0+1] * PW0IS3_C; \
            _Pragma("unroll")                                                     \
            for (int r = 0; r < 4; r++) {                                         \
                sA0[0][r] = fmaf(a0[0][r], dA0, fmaf(a0[2][r], dA1, sA0[0][r]));  \
                sA0[1][r] = fmaf(a0[1][r], dA0, fmaf(a0[3][r], dA1, sA0[1][r]));  \
                sA1[0][r] = fmaf(a1[0][r], dB0, fmaf(a1[2][r], dB1, sA1[0][r]));  \
                sA1[1][r] = fmaf(a1[1][r], dB0, fmaf(a1[3][r], dB1, sA1[1][r]));  \
            }                                                                     \
        } }

    // --- main loop: 18 pair-iterations, one barrier each ---
    // Ledger: barrier@p guarantees all waves finished compute(pair p-1), so
    // STAGEPAIR(p+1) may overwrite pairbuf[(p+1)&1] (= pairbuf[(p-1)&1]).
    // vmcnt(4) after issuing pair p+1's 4 loads waits pair p fully landed.
    f32x4 pA[4], pB[4], qA[4], qB[4];
    for (int p = 0; p < 18; ++p) {
        __builtin_amdgcn_s_barrier();
        if (p < 17) {
            STAGEPAIR(p + 1, (p + 1) & 1)
            asm volatile("s_waitcnt vmcnt(4)" ::: "memory");
        } else {
            asm volatile("s_waitcnt vmcnt(0)" ::: "memory");
        }
        __builtin_amdgcn_sched_barrier(0);
        const int c0 = 2 * p, c1 = 2 * p + 1;
        GEMM2(c0, pA, pB)
        GEMM2(c1, qA, qB)
        EPI(c0, pA, pB)
        EPI(c1, qA, qB)
    }
    #undef GEMM2
    #undef EPI
    #undef STAGEPAIR

    // --- scatter in 2 passes of 64 edges; msg aliases stage pool (dead) ---
    #pragma unroll
    for (int pass = 0; pass < 2; ++pass) {
        __syncthreads();                    // all compute done / previous pass reads done
        if ((wv >> 1) == pass) {
            const int lr0 = (wv & 1) * 32 + l15;   // local rows within this pass
            const int lr1 = lr0 + 16;
            #pragma unroll
            for (int hi = 0; hi < 2; hi++)
                #pragma unroll
                for (int r = 0; r < 4; r++) {
                    msg[lr0][hi * 16 + lk * 4 + r] = sA0[hi][r];
                    msg[lr1][hi * 16 + lk * 4 + r] = sA1[hi][r];
                }
            #pragma unroll
            for (int r = 0; r < 4; r++) {
                const int w = lk * 4 + r;
                #pragma unroll
                for (int k = 0; k < 3; k++) {
                    msg[lr0][32 + w * 3 + k] = C1_C * (sB0[r] * shv_s[eA][k] + sh0A * sC0[k][r]);
                    msg[lr1][32 + w * 3 + k] = C1_C * (sB1[r] * shv_s[eB][k] + sh0B * sC1[k][r]);
                }
            }
        }
        __syncthreads();                    // msg tile ready
        const int ebase = pass * 64;
        for (int i = t; i < 64 * 80; i += 256) {
            const int rr = i / 80, m = i - rr * 80;
            atomicAdd(&agg[(size_t)dst_s[ebase + rr] * 80 + m], msg[rr][m]);
        }
    }
}

// ---------------- fallback f32 edge kernel (proven R3) ----------------
__global__ __launch_bounds__(256, 1) void edge_kernel_f32(
    const float* __restrict__ nf, const int* __restrict__ ei,
    const float* __restrict__ sh, const float* __restrict__ emb,
    const float* __restrict__ rW1, const float* __restrict__ rb1,
    const float* __restrict__ rW2, const float* __restrict__ rb2,
    float* __restrict__ agg)
{
    __shared__ float hT[64][68];
    __shared__ float tpw[64][132];
    __shared__ float xs_s[64][32];
    __shared__ float xv_s[64][48];
    __shared__ float dv_s[64][16];
    __shared__ float sh0_s[64];
    __shared__ float shv_s[64][3];
    __shared__ int   dst_s[64];
    __shared__ float msg[64][84];

    const int t  = threadIdx.x;
    const int e0 = blockIdx.x * 64;
    if (t < 64) {
        const int eid = e0 + t;
        dst_s[t] = ei[N_EDGES_C + eid];
        const float4 s4 = *reinterpret_cast<const float4*>(sh + (size_t)eid * 4);
        sh0_s[t] = s4.x; shv_s[t][0] = s4.y; shv_s[t][1] = s4.z; shv_s[t][2] = s4.w;
    }
    for (int i = t; i < 64 * 84; i += 256) (&msg[0][0])[i] = 0.0f;
    {
        const int e = t >> 2, q = t & 3;
        const int src = ei[e0 + e];
        const float* p = nf + (size_t)src * 80 + q * 20;
        #pragma unroll
        for (int f4 = 0; f4 < 5; f4++) {
            const float4 v = *reinterpret_cast<const float4*>(p + f4 * 4);
            const int g = q * 20 + f4 * 4;
            const float vv[4] = {v.x, v.y, v.z, v.w};
            #pragma unroll
            for (int ii = 0; ii < 4; ii++) {
                const int gg = g + ii;
                if (gg < 32) xs_s[e][gg] = vv[ii]; else xv_s[e][gg - 32] = vv[ii];
            }
        }
    }
    {
        const int c = t & 63, eg = t >> 6;
        float w1[8];
        #pragma unroll
        for (int b = 0; b < 8; b++) w1[b] = rW1[b * 64 + c];
        const float bias = rb1[c];
        #pragma unroll
        for (int rep = 0; rep < 16; rep++) {
            const int e = rep * 4 + eg;
            const float* em = emb + (size_t)(e0 + e) * 8;
            float pre = bias;
            #pragma unroll
            for (int b = 0; b < 8; b++) pre = fmaf(em[b], w1[b], pre);
            hT[c][e] = silu_f(pre);
        }
    }
    __syncthreads();
    {
        const int e = t >> 2, q = t & 3;
        #pragma unroll
        for (int i = 0; i < 4; i++) {
            const int u = q * 4 + i;
            dv_s[e][u] = xv_s[e][u*3+0]*shv_s[e][0] + xv_s[e][u*3+1]*shv_s[e][1]
                       + xv_s[e][u*3+2]*shv_s[e][2];
        }
    }
    __syncthreads();
    const int lane = t & 63, wv = t >> 6;
    for (int ch = 0; ch < 18; ch++) {
        const int jb = ch * 128;
        float acc[16][2];
        #pragma unroll
        for (int i = 0; i < 16; i++) { acc[i][0] = 0.0f; acc[i][1] = 0.0f; }
        const float* Bp = rW2 + jb + lane * 2;
        #pragma unroll 2
        for (int c = 0; c < 64; c++) {
            const float2 b = *reinterpret_cast<const float2*>(Bp + (size_t)c * 2304);
            const float4* ap = reinterpret_cast<const float4*>(&hT[c][wv * 16]);
            const float4 a0 = ap[0], a1 = ap[1], a2 = ap[2], a3 = ap[3];
            const float va[16] = {a0.x,a0.y,a0.z,a0.w, a1.x,a1.y,a1.z,a1.w,
                                  a2.x,a2.y,a2.z,a2.w, a3.x,a3.y,a3.z,a3.w};
            #pragma unroll
            for (int i = 0; i < 16; i++) {
                acc[i][0] = fmaf(va[i], b.x, acc[i][0]);
                acc[i][1] = fmaf(va[i], b.y, acc[i][1]);
            }
        }
        const float2 rb = *reinterpret_cast<const float2*>(rb2 + jb + lane * 2);
        __syncthreads();
        #pragma unroll
        for (int i = 0; i < 16; i++)
            *reinterpret_cast<float2*>(&tpw[wv * 16 + i][lane * 2]) =
                make_float2(acc[i][0] + rb.x, acc[i][1] + rb.y);
        __syncthreads();
        if (ch < 8) {
            const int u0 = ch * 4, w = t & 31, eg = t >> 5;
            #pragma unroll
            for (int ee = 0; ee < 8; ee++) {
                const int e = eg * 8 + ee;
                float s = 0.0f;
                #pragma unroll
                for (int du = 0; du < 4; du++) s = fmaf(tpw[e][du * 32 + w], xs_s[e][u0 + du], s);
                msg[e][w] = fmaf(PW0_C * sh0_s[e], s, msg[e][w]);
            }
        } else if (ch < 12) {
            const int u0 = (ch - 8) * 8, w = t & 15, eg = t >> 4;
            #pragma unroll
            for (int ee = 0; ee < 4; ee++) {
                const int e = eg * 4 + ee;
                float s = 0.0f;
                #pragma unroll
                for (int du = 0; du < 8; du++) s = fmaf(tpw[e][du * 16 + w], xs_s[e][u0 + du], s);
                const float c1s = C1_C * s;
                msg[e][32 + w*3 + 0] = fmaf(c1s, shv_s[e][0], msg[e][32 + w*3 + 0]);
                msg[e][32 + w*3 + 1] = fmaf(c1s, shv_s[e][1], msg[e][32 + w*3 + 1]);
                msg[e][32 + w*3 + 2] = fmaf(c1s, shv_s[e][2], msg[e][32 + w*3 + 2]);
            }
        } else if (ch < 14) {
            const int u0 = (ch - 12) * 8, w = t & 15, eg = t >> 4;
            #pragma unroll
            for (int ee = 0; ee < 4; ee++) {
                const int e = eg * 4 + ee;
                float s0 = 0, s1 = 0, s2 = 0;
                #pragma unroll
                for (int du = 0; du < 8; du++) {
                    const float tv = tpw[e][du * 16 + w];
                    const int u = u0 + du;
                    s0 = fmaf(tv, xv_s[e][u*3 + 0], s0);
                    s1 = fmaf(tv, xv_s[e][u*3 + 1], s1);
                    s2 = fmaf(tv, xv_s[e][u*3 + 2], s2);
                }
                const float f = C1_C * sh0_s[e];
                msg[e][32 + w*3 + 0] = fmaf(f, s0, msg[e][32 + w*3 + 0]);
                msg[e][32 + w*3 + 1] = fmaf(f, s1, msg[e][32 + w*3 + 1]);
                msg[e][32 + w*3 + 2] = fmaf(f, s2, msg[e][32 + w*3 + 2]);
            }
        } else {
            const int u0 = (ch - 14) * 4, w = t & 31, eg = t >> 5;
            #pragma unroll
            for (int ee = 0; ee < 8; ee++) {
                const int e = eg * 8 + ee;
                float s = 0.0f;
                #pragma unroll
                for (int du = 0; du < 4; du++) s = fmaf(tpw[e][du * 32 + w], dv_s[e][u0 + du], s);
                msg[e][w] = fmaf(PW0IS3_C, s, msg[e][w]);
            }
        }
    }
    __syncthreads();
    for (int i = t; i < 64 * 80; i += 256) {
        const int e = i / 80, m = i - e * 80;
        atomicAdd(&agg[(size_t)dst_s[e] * 80 + m], msg[e][m]);
    }
}

// Node update, IN PLACE on io (= d_out, holding agg).
__global__ __launch_bounds__(256, 4) void node_kernel(
    const float* __restrict__ nf,
    float* __restrict__ io,
    const float* __restrict__ Wl0,
    const float* __restrict__ Wl1)
{
    __shared__ float a_s[4][80];
    const int t  = threadIdx.x;
    const int nb = blockIdx.x * 4;
    for (int i = t; i < 320; i += 256)
        a_s[i / 80][i % 80] = io[(size_t)nb * 80 + i];
    __syncthreads();

    const int ln = t >> 6;
    const int r  = t & 63;
    const int n  = nb + ln;
    const float* a = a_s[ln];
    if (r < 32) {
        float s = 0.0f;
        #pragma unroll
        for (int u = 0; u < 32; u++) s = fmaf(a[u], Wl0[u * 32 + r], s);
        s *= RS32_C;
        io[(size_t)n * 80 + r] = nf[(size_t)n * 80 + r] + silu_f(s);
    } else if (r < 48) {
        const int v = r - 32;
        float l0 = 0, l1 = 0, l2 = 0;
        #pragma unroll
        for (int u = 0; u < 16; u++) {
            const float w = Wl1[u * 16 + v];
            l0 = fmaf(a[32 + u*3 + 0], w, l0);
            l1 = fmaf(a[32 + u*3 + 1], w, l1);
            l2 = fmaf(a[32 + u*3 + 2], w, l2);
        }
        l0 *= 0.25f; l1 *= 0.25f; l2 *= 0.25f;
        const float norm = sqrtf(l0*l0 + l1*l1 + l2*l2);
        float f = 0.0f;
        if (norm >= 1e-8f) f = silu_f(norm) / norm;
        const size_t o = (size_t)n * 80 + 32 + (size_t)v * 3;
        io[o + 0] = nf[o + 0] + f * l0;
        io[o + 1] = nf[o + 1] + f * l1;
        io[o + 2] = nf[o + 2] + f * l2;
    }
}

extern "C" void kernel_launch(void* const* d_in, const int* in_sizes, int n_in,
                              void* d_out, int out_size, void* d_ws, size_t ws_size,
                              hipStream_t stream) {
    const float* nf  = (const float*)d_in[0];
    const int*   ei  = (const int*)d_in[1];
    const float* sh  = (const float*)d_in[2];
    const float* emb = (const float*)d_in[3];
    const float* rW1 = (const float*)d_in[4];
    const float* rb1 = (const float*)d_in[5];
    const float* rW2 = (const float*)d_in[6];
    const float* rb2 = (const float*)d_in[7];
    const float* Wl0 = (const float*)d_in[8];
    const float* Wl1 = (const float*)d_in[9];

    float* agg = (float*)d_out;
    hipMemsetAsync(agg, 0, (size_t)N_NODES_C * 80 * sizeof(float), stream);

    const size_t rW2T_bytes = (size_t)2304 * 64 * sizeof(unsigned short);
    if (d_ws != nullptr && ws_size >= rW2T_bytes) {
        unsigned short* rW2T = (unsigned short*)d_ws;
        prep_kernel<<<(2304 * 64) / 256, 256, 0, stream>>>(rW2, rW2T);
        edge_kernel_mfma<<<N_EDGES_C / 128, 256, 0, stream>>>(
            nf, ei, sh, emb, rW1, rb1, rW2T, rb2, agg);
    } else {
        edge_kernel_f32<<<N_EDGES_C / 64, 256, 0, stream>>>(
            nf, ei, sh, emb, rW1, rb1, rW2, rb2, agg);
    }
    node_kernel<<<N_NODES_C / 4, 256, 0, stream>>>(nf, agg, Wl0, Wl1);
}